// Round 1
// baseline (2115.763 us; speedup 1.0000x reference)
//
#include <hip/hip_runtime.h>
#include <hip/hip_bf16.h>

#define N_NODES 30000
#define N_EDGES 240000
#define ETOT    (N_EDGES + N_NODES)   // 270000 (self loops appended)
#define NGRAPH  128

__device__ __forceinline__ void atomicMaxFloat(float* addr, float val) {
    // works with init bit pattern 0xFFFFFFFF (negative NaN): int=-1, uint=max
    if (val >= 0.f) atomicMax((int*)addr, __float_as_int(val));
    else            atomicMin((unsigned int*)addr, (unsigned int)__float_as_int(val));
}

// ---------------- GEMM: C[M,ncols] = A[M,128] @ B[128,ncols] ----------------
__global__ __launch_bounds__(256) void gemm_k128(const float* __restrict__ A,
                                                 const float* __restrict__ B,
                                                 float* __restrict__ C,
                                                 int M, int ncols) {
    __shared__ float As[64 * 132];   // padded stride 132 (bank-conflict)
    __shared__ float Bs[128 * 64];
    const int bm = blockIdx.x * 64;
    const int bn = blockIdx.y * 64;
    const int t  = threadIdx.x;

    // A tile: rows bm..bm+63, all K=128 (contiguous 32KB block of A)
#pragma unroll
    for (int k = 0; k < 8; k++) {
        int idx4 = t + k * 256;          // 0..2047 float4 slots
        int row  = idx4 >> 5;            // 32 float4 per row
        int c4   = (idx4 & 31) << 2;
        float4 v = make_float4(0.f, 0.f, 0.f, 0.f);
        if (bm + row < M) v = *(const float4*)(A + (size_t)(bm + row) * 128 + c4);
        *(float4*)(As + row * 132 + c4) = v;
    }
    // B tile: rows 0..127, cols bn..bn+63
#pragma unroll
    for (int k = 0; k < 8; k++) {
        int idx4 = t + k * 256;
        int row  = idx4 >> 4;            // 16 float4 per row
        int c4   = (idx4 & 15) << 2;
        float4 v = *(const float4*)(B + (size_t)row * ncols + bn + c4);
        *(float4*)(Bs + row * 64 + c4) = v;
    }
    __syncthreads();

    const int ty = t >> 4, tx = t & 15;
    const int r0 = ty * 4, c0 = tx * 4;
    float acc[4][4] = {};
#pragma unroll 4
    for (int k = 0; k < 128; k++) {
        float4 b4 = *(const float4*)(Bs + k * 64 + c0);
#pragma unroll
        for (int i = 0; i < 4; i++) {
            float a = As[(r0 + i) * 132 + k];
            acc[i][0] = fmaf(a, b4.x, acc[i][0]);
            acc[i][1] = fmaf(a, b4.y, acc[i][1]);
            acc[i][2] = fmaf(a, b4.z, acc[i][2]);
            acc[i][3] = fmaf(a, b4.w, acc[i][3]);
        }
    }
#pragma unroll
    for (int i = 0; i < 4; i++) {
        int row = bm + r0 + i;
        if (row < M) {
            float4 v = make_float4(acc[i][0], acc[i][1], acc[i][2], acc[i][3]);
            *(float4*)(C + (size_t)row * ncols + bn + c0) = v;
        }
    }
}

// ---------------- attention logits per node ----------------
// al_s[n,h] = sum_c hfull[n, h*128+c] * att_s[h,c]; same for al_d
__global__ __launch_bounds__(256) void alphas_kernel(const float* __restrict__ hfull,
                                                     const float* __restrict__ att_s,
                                                     const float* __restrict__ att_d,
                                                     float* __restrict__ al_s,
                                                     float* __restrict__ al_d) {
    int n = blockIdx.x * 4 + (threadIdx.x >> 6);
    if (n >= N_NODES) return;
    int lane  = threadIdx.x & 63;
    int hd    = lane >> 4;           // 4 heads x 16 lanes
    int cbase = (lane & 15) * 8;     // 8 floats per lane
    const float* hr = hfull + (size_t)n * 512 + hd * 128 + cbase;
    const float* as = att_s + hd * 128 + cbase;
    const float* ad = att_d + hd * 128 + cbase;
    float ss = 0.f, sd = 0.f;
#pragma unroll
    for (int j = 0; j < 8; j++) { float v = hr[j]; ss = fmaf(v, as[j], ss); sd = fmaf(v, ad[j], sd); }
#pragma unroll
    for (int off = 1; off < 16; off <<= 1) { ss += __shfl_xor(ss, off); sd += __shfl_xor(sd, off); }
    if ((lane & 15) == 0) { al_s[n * 4 + hd] = ss; al_d[n * 4 + hd] = sd; }
}

// ---------------- edge pass 1: scores + segment max ----------------
__global__ __launch_bounds__(256) void edge_pass1(const int* __restrict__ ei0,
                                                  const int* __restrict__ ei1,
                                                  const float* __restrict__ al_s,
                                                  const float* __restrict__ al_d,
                                                  float* __restrict__ e,
                                                  float* __restrict__ m) {
    int tid = blockIdx.x * blockDim.x + threadIdx.x;
    if (tid >= ETOT * 4) return;
    int eid = tid >> 2, hd = tid & 3;
    int s = (eid < N_EDGES) ? ei0[eid] : (eid - N_EDGES);
    int d = (eid < N_EDGES) ? ei1[eid] : (eid - N_EDGES);
    float v = al_s[s * 4 + hd] + al_d[d * 4 + hd];
    v = (v > 0.f) ? v : 0.2f * v;           // leaky_relu 0.2
    e[tid] = v;
    atomicMaxFloat(&m[d * 4 + hd], v);
}

// ---------------- edge pass 2: weighted scatter (one wave per edge) ----------------
__global__ __launch_bounds__(256) void edge_pass2(const int* __restrict__ ei0,
                                                  const int* __restrict__ ei1,
                                                  const float* __restrict__ e,
                                                  const float* __restrict__ m,
                                                  const float* __restrict__ hfull,
                                                  float* __restrict__ z,
                                                  float* __restrict__ acc) {
    int wid  = (blockIdx.x * blockDim.x + threadIdx.x) >> 6;
    int lane = threadIdx.x & 63;
    if (wid >= ETOT) return;
    int s = (wid < N_EDGES) ? ei0[wid] : (wid - N_EDGES);
    int d = (wid < N_EDGES) ? ei1[wid] : (wid - N_EDGES);
    float ex0 = __expf(e[wid * 4 + 0] - m[d * 4 + 0]);
    float ex1 = __expf(e[wid * 4 + 1] - m[d * 4 + 1]);
    float ex2 = __expf(e[wid * 4 + 2] - m[d * 4 + 2]);
    float ex3 = __expf(e[wid * 4 + 3] - m[d * 4 + 3]);
    if (lane < 4) {
        float exl = (lane == 0) ? ex0 : (lane == 1) ? ex1 : (lane == 2) ? ex2 : ex3;
        atomicAdd(&z[d * 4 + lane], exl);
    }
    const float* hs = hfull + (size_t)s * 512;
    float* ad = acc + (size_t)d * 512;
    float exs[4] = {ex0, ex1, ex2, ex3};
#pragma unroll
    for (int hd = 0; hd < 4; hd++) {
        float v0 = hs[hd * 128 + lane];
        float v1 = hs[hd * 128 + 64 + lane];
        atomicAdd(&ad[hd * 128 + lane],      exs[hd] * v0);
        atomicAdd(&ad[hd * 128 + 64 + lane], exs[hd] * v1);
    }
}

// ---------------- combine heads + conv bias + BN partial sums ----------------
__global__ __launch_bounds__(256) void combine_kernel(const float* __restrict__ acc,
                                                      const float* __restrict__ z,
                                                      const float* __restrict__ conv_b,
                                                      float* __restrict__ g,
                                                      float* __restrict__ bnsum,
                                                      float* __restrict__ bnsum2) {
    int c    = threadIdx.x & 127;
    int half = threadIdx.x >> 7;
    int n0   = blockIdx.x * 64;
    float cb = conv_b[c];
    float s1 = 0.f, s2 = 0.f;
    for (int i = half; i < 64; i += 2) {
        int n = n0 + i;
        if (n >= N_NODES) continue;
        float v = 0.f;
#pragma unroll
        for (int hd = 0; hd < 4; hd++) {
            float zz = z[n * 4 + hd] + 1e-16f;
            v += acc[(size_t)n * 512 + hd * 128 + c] / zz;
        }
        v = v * 0.25f + cb;
        g[(size_t)n * 128 + c] = v;
        s1 += v; s2 = fmaf(v, v, s2);
    }
    __shared__ float sh[256];
    sh[threadIdx.x] = s1; __syncthreads();
    if (half == 0) atomicAdd(&bnsum[c], sh[c] + sh[c + 128]);
    __syncthreads();
    sh[threadIdx.x] = s2; __syncthreads();
    if (half == 0) atomicAdd(&bnsum2[c], sh[c] + sh[c + 128]);
}

__global__ void bn_final(const float* __restrict__ s1, const float* __restrict__ s2,
                         const float* __restrict__ gamma, const float* __restrict__ beta,
                         float* __restrict__ bnp) {
    int c = threadIdx.x;
    float inv = 1.f / (float)N_NODES;
    float mu  = s1[c] * inv;
    float var = s2[c] * inv - mu * mu;
    float rs  = rsqrtf(var + 1e-5f);
    float sc  = gamma[c] * rs;
    bnp[c]       = sc;
    bnp[128 + c] = beta[c] - mu * sc;
}

__global__ __launch_bounds__(256) void hbn_kernel(const float* __restrict__ g,
                                                  const float* __restrict__ bnp,
                                                  float* __restrict__ hbn) {
    int i = blockIdx.x * blockDim.x + threadIdx.x;
    if (i >= N_NODES * 32) return;
    int c4 = (i & 31) << 2;
    float4 v = ((const float4*)g)[i];
    float4 r;
    r.x = fmaf(bnp[c4 + 0], v.x, bnp[128 + c4 + 0]);
    r.y = fmaf(bnp[c4 + 1], v.y, bnp[128 + c4 + 1]);
    r.z = fmaf(bnp[c4 + 2], v.z, bnp[128 + c4 + 2]);
    r.w = fmaf(bnp[c4 + 3], v.w, bnp[128 + c4 + 3]);
    ((float4*)hbn)[i] = r;
}

__global__ __launch_bounds__(256) void gate_kernel(const float* __restrict__ t1,
                                                   const float* __restrict__ t2,
                                                   const float* __restrict__ hbn,
                                                   const float* __restrict__ idn,
                                                   const float* __restrict__ bin,
                                                   const float* __restrict__ bout,
                                                   float* __restrict__ hout) {
    int i = blockIdx.x * blockDim.x + threadIdx.x;
    if (i >= N_NODES * 32) return;
    int c4 = (i & 31) << 2;
    float4 a = ((const float4*)t1)[i];
    float4 b = ((const float4*)t2)[i];
    float4 h = ((const float4*)hbn)[i];
    float4 d = ((const float4*)idn)[i];
    float4 r;
    {
        float gp = a.x + b.x + bin[c4 + 0] + bout[c4 + 0];
        float gt = 1.f / (1.f + __expf(-gp));
        r.x = fmaxf(gt * h.x + (1.f - gt) * d.x, 0.f);
    }
    {
        float gp = a.y + b.y + bin[c4 + 1] + bout[c4 + 1];
        float gt = 1.f / (1.f + __expf(-gp));
        r.y = fmaxf(gt * h.y + (1.f - gt) * d.y, 0.f);
    }
    {
        float gp = a.z + b.z + bin[c4 + 2] + bout[c4 + 2];
        float gt = 1.f / (1.f + __expf(-gp));
        r.z = fmaxf(gt * h.z + (1.f - gt) * d.z, 0.f);
    }
    {
        float gp = a.w + b.w + bin[c4 + 3] + bout[c4 + 3];
        float gt = 1.f / (1.f + __expf(-gp));
        r.w = fmaxf(gt * h.w + (1.f - gt) * d.w, 0.f);
    }
    ((float4*)hout)[i] = r;
}

__global__ __launch_bounds__(256) void pool_kernel(const float* __restrict__ h,
                                                   const int* __restrict__ batch,
                                                   float* __restrict__ pooled,
                                                   float* __restrict__ cnt) {
    int i = blockIdx.x * blockDim.x + threadIdx.x;
    if (i >= N_NODES * 128) return;
    int n = i >> 7, c = i & 127;
    int b = batch[n];
    atomicAdd(&pooled[b * 128 + c], h[i]);
    if (c == 0) atomicAdd(&cnt[b], 1.f);
}

__global__ __launch_bounds__(128) void head_kernel(const float* __restrict__ pooled,
                                                   const float* __restrict__ cnt,
                                                   const float* __restrict__ fc1W,
                                                   const float* __restrict__ fc1b,
                                                   const float* __restrict__ fc3W,
                                                   const float* __restrict__ fc3b,
                                                   float* __restrict__ out) {
    int gid = blockIdx.x, t = threadIdx.x;
    __shared__ float hg[128];
    __shared__ float a1[128];
    float cc = fmaxf(cnt[gid], 1.f);
    hg[t] = pooled[gid * 128 + t] / cc;
    __syncthreads();
    float s = fc1b[t];
    for (int c = 0; c < 128; c++) s = fmaf(hg[c], fc1W[c * 128 + t], s);
    a1[t] = fmaxf(s, 0.f);
    __syncthreads();
    if (t < 16) {
        float o = fc3b[t];
        for (int j = 0; j < 128; j++) o = fmaf(a1[j], fc3W[j * 16 + t], o);
        out[gid * 16 + t] = o;
    }
}

extern "C" void kernel_launch(void* const* d_in, const int* in_sizes, int n_in,
                              void* d_out, int out_size, void* d_ws, size_t ws_size,
                              hipStream_t stream) {
    const float* x       = (const float*)d_in[0];
    const int*   ei      = (const int*)d_in[1];
    const int*   batch   = (const int*)d_in[2];
    const float* W       = (const float*)d_in[3];
    const float* att_src = (const float*)d_in[4];
    const float* att_dst = (const float*)d_in[5];
    const float* conv_b  = (const float*)d_in[6];
    const float* gamma   = (const float*)d_in[7];
    const float* beta    = (const float*)d_in[8];
    const float* sk_Win  = (const float*)d_in[9];
    const float* sk_bin  = (const float*)d_in[10];
    const float* sk_Wout = (const float*)d_in[11];
    const float* sk_bout = (const float*)d_in[12];
    const float* fc1_W   = (const float*)d_in[13];
    const float* fc1_b   = (const float*)d_in[14];
    const float* fc3_W   = (const float*)d_in[15];
    const float* fc3_b   = (const float*)d_in[16];
    float* out = (float*)d_out;
    const int* ei0 = ei;
    const int* ei1 = ei + N_EDGES;

    float* ws = (float*)d_ws;
    size_t o = 0;
    float* hfull  = ws + o; o += (size_t)N_NODES * 512;
    float* acc    = ws + o; o += (size_t)N_NODES * 512;
    float* ebuf   = ws + o; o += (size_t)ETOT * 4;
    float* mbuf   = ws + o; o += N_NODES * 4;
    float* zbuf   = ws + o; o += N_NODES * 4;
    float* als    = ws + o; o += N_NODES * 4;
    float* ald    = ws + o; o += N_NODES * 4;
    float* gbuf   = ws + o; o += (size_t)N_NODES * 128;
    float* hbn    = ws + o; o += (size_t)N_NODES * 128;
    float* hA     = ws + o; o += (size_t)N_NODES * 128;
    float* hB     = ws + o; o += (size_t)N_NODES * 128;
    float* bnsum  = ws + o; o += 128;
    float* bnsum2 = ws + o; o += 128;
    float* bnp    = ws + o; o += 256;
    float* pooled = ws + o; o += NGRAPH * 128;
    float* cnt    = ws + o; o += NGRAPH;
    // t1/t2 alias hfull (hfull dead after edge_pass2 / alphas)
    float* t1 = hfull;
    float* t2 = hfull + (size_t)N_NODES * 128;

    const float* hin = x;
    float* hout = hA;
    for (int l = 0; l < 3; l++) {
        hipMemsetAsync(acc,    0,    (size_t)N_NODES * 512 * 4, stream);
        hipMemsetAsync(zbuf,   0,    N_NODES * 4 * 4, stream);
        hipMemsetAsync(mbuf,   0xFF, N_NODES * 4 * 4, stream);
        hipMemsetAsync(bnsum,  0,    128 * 4, stream);
        hipMemsetAsync(bnsum2, 0,    128 * 4, stream);

        gemm_k128<<<dim3(469, 8), 256, 0, stream>>>(hin, W + (size_t)l * 128 * 512, hfull, N_NODES, 512);
        alphas_kernel<<<7500, 256, 0, stream>>>(hfull, att_src + l * 512, att_dst + l * 512, als, ald);
        edge_pass1<<<(ETOT * 4 + 255) / 256, 256, 0, stream>>>(ei0, ei1, als, ald, ebuf, mbuf);
        edge_pass2<<<(ETOT * 64 + 255) / 256, 256, 0, stream>>>(ei0, ei1, ebuf, mbuf, hfull, zbuf, acc);
        combine_kernel<<<469, 256, 0, stream>>>(acc, zbuf, conv_b + l * 128, gbuf, bnsum, bnsum2);
        bn_final<<<1, 128, 0, stream>>>(bnsum, bnsum2, gamma + l * 128, beta + l * 128, bnp);
        hbn_kernel<<<(N_NODES * 32 + 255) / 256, 256, 0, stream>>>(gbuf, bnp, hbn);
        gemm_k128<<<dim3(469, 2), 256, 0, stream>>>(hin, sk_Win + (size_t)l * 128 * 128, t1, N_NODES, 128);
        gemm_k128<<<dim3(469, 2), 256, 0, stream>>>(hbn, sk_Wout + (size_t)l * 128 * 128, t2, N_NODES, 128);
        gate_kernel<<<(N_NODES * 32 + 255) / 256, 256, 0, stream>>>(t1, t2, hbn, hin,
                                                                    sk_bin + l * 128, sk_bout + l * 128, hout);
        hin = hout;
        hout = (hout == hA) ? hB : hA;
    }

    hipMemsetAsync(pooled, 0, NGRAPH * 128 * 4, stream);
    hipMemsetAsync(cnt,    0, NGRAPH * 4, stream);
    pool_kernel<<<(N_NODES * 128 + 255) / 256, 256, 0, stream>>>(hin, batch, pooled, cnt);
    head_kernel<<<NGRAPH, 128, 0, stream>>>(pooled, cnt, fc1_W, fc1_b, fc3_W, fc3_b, out);
}

// Round 2
// 978.712 us; speedup vs baseline: 2.1618x; 2.1618x over previous
//
#include <hip/hip_runtime.h>
#include <hip/hip_bf16.h>

#define N_NODES 30000
#define N_EDGES 240000
#define ETOT    (N_EDGES + N_NODES)   // 270000 (self loops appended)
#define NGRAPH  128

// ---------------- GEMM: C[M,ncols] = A[M,128] @ B[128,ncols] ----------------
__global__ __launch_bounds__(256) void gemm_k128(const float* __restrict__ A,
                                                 const float* __restrict__ B,
                                                 float* __restrict__ C,
                                                 int M, int ncols) {
    __shared__ float As[64 * 132];   // padded stride 132 (bank-conflict)
    __shared__ float Bs[128 * 64];
    const int bm = blockIdx.x * 64;
    const int bn = blockIdx.y * 64;
    const int t  = threadIdx.x;

#pragma unroll
    for (int k = 0; k < 8; k++) {
        int idx4 = t + k * 256;          // 0..2047 float4 slots
        int row  = idx4 >> 5;            // 32 float4 per row
        int c4   = (idx4 & 31) << 2;
        float4 v = make_float4(0.f, 0.f, 0.f, 0.f);
        if (bm + row < M) v = *(const float4*)(A + (size_t)(bm + row) * 128 + c4);
        *(float4*)(As + row * 132 + c4) = v;
    }
#pragma unroll
    for (int k = 0; k < 8; k++) {
        int idx4 = t + k * 256;
        int row  = idx4 >> 4;            // 16 float4 per row
        int c4   = (idx4 & 15) << 2;
        float4 v = *(const float4*)(B + (size_t)row * ncols + bn + c4);
        *(float4*)(Bs + row * 64 + c4) = v;
    }
    __syncthreads();

    const int ty = t >> 4, tx = t & 15;
    const int r0 = ty * 4, c0 = tx * 4;
    float acc[4][4] = {};
#pragma unroll 4
    for (int k = 0; k < 128; k++) {
        float4 b4 = *(const float4*)(Bs + k * 64 + c0);
#pragma unroll
        for (int i = 0; i < 4; i++) {
            float a = As[(r0 + i) * 132 + k];
            acc[i][0] = fmaf(a, b4.x, acc[i][0]);
            acc[i][1] = fmaf(a, b4.y, acc[i][1]);
            acc[i][2] = fmaf(a, b4.z, acc[i][2]);
            acc[i][3] = fmaf(a, b4.w, acc[i][3]);
        }
    }
#pragma unroll
    for (int i = 0; i < 4; i++) {
        int row = bm + r0 + i;
        if (row < M) {
            float4 v = make_float4(acc[i][0], acc[i][1], acc[i][2], acc[i][3]);
            *(float4*)(C + (size_t)row * ncols + bn + c0) = v;
        }
    }
}

// ---------------- attention logits per node ----------------
__global__ __launch_bounds__(256) void alphas_kernel(const float* __restrict__ hfull,
                                                     const float* __restrict__ att_s,
                                                     const float* __restrict__ att_d,
                                                     float* __restrict__ al_s,
                                                     float* __restrict__ al_d) {
    int n = blockIdx.x * 4 + (threadIdx.x >> 6);
    if (n >= N_NODES) return;
    int lane  = threadIdx.x & 63;
    int hd    = lane >> 4;           // 4 heads x 16 lanes
    int cbase = (lane & 15) * 8;     // 8 floats per lane
    const float* hr = hfull + (size_t)n * 512 + hd * 128 + cbase;
    const float* as = att_s + hd * 128 + cbase;
    const float* ad = att_d + hd * 128 + cbase;
    float ss = 0.f, sd = 0.f;
#pragma unroll
    for (int j = 0; j < 8; j++) { float v = hr[j]; ss = fmaf(v, as[j], ss); sd = fmaf(v, ad[j], sd); }
#pragma unroll
    for (int off = 1; off < 16; off <<= 1) { ss += __shfl_xor(ss, off); sd += __shfl_xor(sd, off); }
    if ((lane & 15) == 0) { al_s[n * 4 + hd] = ss; al_d[n * 4 + hd] = sd; }
}

// ---------------- CSR build (once per launch; edge_index is layer-invariant) ----
__global__ __launch_bounds__(256) void deg_kernel(const int* __restrict__ ei1,
                                                  int* __restrict__ deg) {
    int e = blockIdx.x * 256 + threadIdx.x;
    if (e >= ETOT) return;
    int d = (e < N_EDGES) ? ei1[e] : (e - N_EDGES);
    atomicAdd(&deg[d], 1);
}

__global__ __launch_bounds__(1024) void scan_kernel(const int* __restrict__ deg,
                                                    int* __restrict__ rowptr,
                                                    int* __restrict__ wofs) {
    const int CH = 30;  // 1024*30 = 30720 >= 30001
    int t = threadIdx.x;
    int base = t * CH;
    int s = 0;
    for (int j = 0; j < CH; j++) { int idx = base + j; if (idx < N_NODES) s += deg[idx]; }
    __shared__ int sums[1024];
    sums[t] = s;
    __syncthreads();
    for (int off = 1; off < 1024; off <<= 1) {
        int v = (t >= off) ? sums[t - off] : 0;
        __syncthreads();
        sums[t] += v;
        __syncthreads();
    }
    int run = sums[t] - s;   // exclusive prefix
    for (int j = 0; j < CH; j++) {
        int idx = base + j;
        if (idx < N_NODES) { rowptr[idx] = run; wofs[idx] = run; run += deg[idx]; }
        else if (idx == N_NODES) { rowptr[N_NODES] = run; }
    }
}

__global__ __launch_bounds__(256) void scatter_kernel(const int* __restrict__ ei0,
                                                      const int* __restrict__ ei1,
                                                      int* __restrict__ wofs,
                                                      int* __restrict__ csr_src) {
    int e = blockIdx.x * 256 + threadIdx.x;
    if (e >= ETOT) return;
    int s = (e < N_EDGES) ? ei0[e] : (e - N_EDGES);
    int d = (e < N_EDGES) ? ei1[e] : (e - N_EDGES);
    int pos = atomicAdd(&wofs[d], 1);
    csr_src[pos] = s;
}

// ---------------- fused gather: softmax + weighted agg + head-mean + bias + BN stats
// one wave per dst node (grid-stride). lane l holds hfull columns [8l, 8l+8).
__global__ __launch_bounds__(256) void gat_gather(const int* __restrict__ rowptr,
                                                  const int* __restrict__ csr_src,
                                                  const float* __restrict__ al_s,
                                                  const float* __restrict__ al_d,
                                                  const float* __restrict__ hfull,
                                                  const float* __restrict__ conv_b,
                                                  float* __restrict__ g,
                                                  float* __restrict__ bnsum,
                                                  float* __restrict__ bnsum2) {
    const int lane = threadIdx.x & 63;
    const int wib  = threadIdx.x >> 6;
    const int gwid = blockIdx.x * 4 + wib;
    const int nw   = gridDim.x * 4;
    const int h    = lane >> 4;      // head of this lane
    const int sub  = lane & 15;
    float s1[8] = {}, s2[8] = {};

    for (int n = gwid; n < N_NODES; n += nw) {
        const int e0 = rowptr[n], e1 = rowptr[n + 1];
        const float ald_h = al_d[n * 4 + h];

        // pass A: segment max per head (16 lanes per head stride the edge list)
        float mx = -1e30f;
        for (int i = e0 + sub; i < e1; i += 16) {
            int s = csr_src[i];
            float v = al_s[s * 4 + h] + ald_h;
            v = (v > 0.f) ? v : 0.2f * v;
            mx = fmaxf(mx, v);
        }
        mx = fmaxf(mx, __shfl_xor(mx, 1));
        mx = fmaxf(mx, __shfl_xor(mx, 2));
        mx = fmaxf(mx, __shfl_xor(mx, 4));
        mx = fmaxf(mx, __shfl_xor(mx, 8));

        // pass B: weighted accumulate (2-edge unroll for MLP)
        float acc[8] = {};
        float zs = 0.f;
        int i = e0;
        for (; i + 1 < e1; i += 2) {
            int sA = csr_src[i], sB = csr_src[i + 1];
            float vA = al_s[sA * 4 + h] + ald_h; vA = (vA > 0.f) ? vA : 0.2f * vA;
            float vB = al_s[sB * 4 + h] + ald_h; vB = (vB > 0.f) ? vB : 0.2f * vB;
            const float4* pA = (const float4*)(hfull + (size_t)sA * 512) + (lane << 1);
            const float4* pB = (const float4*)(hfull + (size_t)sB * 512) + (lane << 1);
            float4 a0 = pA[0], a1 = pA[1];
            float4 b0 = pB[0], b1 = pB[1];
            float exA = __expf(vA - mx), exB = __expf(vB - mx);
            zs += exA + exB;
            acc[0] = fmaf(exA, a0.x, acc[0]); acc[1] = fmaf(exA, a0.y, acc[1]);
            acc[2] = fmaf(exA, a0.z, acc[2]); acc[3] = fmaf(exA, a0.w, acc[3]);
            acc[4] = fmaf(exA, a1.x, acc[4]); acc[5] = fmaf(exA, a1.y, acc[5]);
            acc[6] = fmaf(exA, a1.z, acc[6]); acc[7] = fmaf(exA, a1.w, acc[7]);
            acc[0] = fmaf(exB, b0.x, acc[0]); acc[1] = fmaf(exB, b0.y, acc[1]);
            acc[2] = fmaf(exB, b0.z, acc[2]); acc[3] = fmaf(exB, b0.w, acc[3]);
            acc[4] = fmaf(exB, b1.x, acc[4]); acc[5] = fmaf(exB, b1.y, acc[5]);
            acc[6] = fmaf(exB, b1.z, acc[6]); acc[7] = fmaf(exB, b1.w, acc[7]);
        }
        if (i < e1) {
            int sA = csr_src[i];
            float vA = al_s[sA * 4 + h] + ald_h; vA = (vA > 0.f) ? vA : 0.2f * vA;
            const float4* pA = (const float4*)(hfull + (size_t)sA * 512) + (lane << 1);
            float4 a0 = pA[0], a1 = pA[1];
            float exA = __expf(vA - mx);
            zs += exA;
            acc[0] = fmaf(exA, a0.x, acc[0]); acc[1] = fmaf(exA, a0.y, acc[1]);
            acc[2] = fmaf(exA, a0.z, acc[2]); acc[3] = fmaf(exA, a0.w, acc[3]);
            acc[4] = fmaf(exA, a1.x, acc[4]); acc[5] = fmaf(exA, a1.y, acc[5]);
            acc[6] = fmaf(exA, a1.z, acc[6]); acc[7] = fmaf(exA, a1.w, acc[7]);
        }

        // normalize per head, mean over heads via butterfly on lane bits 4,5
        float inv = 0.25f / (zs + 1e-16f);
#pragma unroll
        for (int j = 0; j < 8; j++) {
            float a = acc[j] * inv;
            a += __shfl_xor(a, 16);
            a += __shfl_xor(a, 32);
            acc[j] = a;
        }
        if (lane < 16) {
            float o[8];
#pragma unroll
            for (int j = 0; j < 8; j++) {
                float t = acc[j] + conv_b[sub * 8 + j];
                o[j] = t;
                s1[j] += t;
                s2[j] = fmaf(t, t, s2[j]);
            }
            float* gp = g + (size_t)n * 128 + sub * 8;
            *(float4*)gp       = make_float4(o[0], o[1], o[2], o[3]);
            *(float4*)(gp + 4) = make_float4(o[4], o[5], o[6], o[7]);
        }
    }

    // BN partial-sum reduce: LDS across the block's 4 waves, one atomic per col
    __shared__ float redA[4][128], redB[4][128];
    if (lane < 16) {
#pragma unroll
        for (int j = 0; j < 8; j++) {
            redA[wib][sub * 8 + j] = s1[j];
            redB[wib][sub * 8 + j] = s2[j];
        }
    }
    __syncthreads();
    int t = threadIdx.x;
    if (t < 128) {
        atomicAdd(&bnsum[t], redA[0][t] + redA[1][t] + redA[2][t] + redA[3][t]);
    } else {
        int c = t - 128;
        atomicAdd(&bnsum2[c], redB[0][c] + redB[1][c] + redB[2][c] + redB[3][c]);
    }
}

__global__ void bn_final(const float* __restrict__ s1, const float* __restrict__ s2,
                         const float* __restrict__ gamma, const float* __restrict__ beta,
                         float* __restrict__ bnp) {
    int c = threadIdx.x;
    float inv = 1.f / (float)N_NODES;
    float mu  = s1[c] * inv;
    float var = s2[c] * inv - mu * mu;
    float rs  = rsqrtf(var + 1e-5f);
    float sc  = gamma[c] * rs;
    bnp[c]       = sc;
    bnp[128 + c] = beta[c] - mu * sc;
}

__global__ __launch_bounds__(256) void hbn_kernel(const float* __restrict__ g,
                                                  const float* __restrict__ bnp,
                                                  float* __restrict__ hbn) {
    int i = blockIdx.x * blockDim.x + threadIdx.x;
    if (i >= N_NODES * 32) return;
    int c4 = (i & 31) << 2;
    float4 v = ((const float4*)g)[i];
    float4 r;
    r.x = fmaf(bnp[c4 + 0], v.x, bnp[128 + c4 + 0]);
    r.y = fmaf(bnp[c4 + 1], v.y, bnp[128 + c4 + 1]);
    r.z = fmaf(bnp[c4 + 2], v.z, bnp[128 + c4 + 2]);
    r.w = fmaf(bnp[c4 + 3], v.w, bnp[128 + c4 + 3]);
    ((float4*)hbn)[i] = r;
}

__global__ __launch_bounds__(256) void gate_kernel(const float* __restrict__ t1,
                                                   const float* __restrict__ t2,
                                                   const float* __restrict__ hbn,
                                                   const float* __restrict__ idn,
                                                   const float* __restrict__ bin,
                                                   const float* __restrict__ bout,
                                                   float* __restrict__ hout) {
    int i = blockIdx.x * blockDim.x + threadIdx.x;
    if (i >= N_NODES * 32) return;
    int c4 = (i & 31) << 2;
    float4 a = ((const float4*)t1)[i];
    float4 b = ((const float4*)t2)[i];
    float4 h = ((const float4*)hbn)[i];
    float4 d = ((const float4*)idn)[i];
    float4 r;
    {
        float gp = a.x + b.x + bin[c4 + 0] + bout[c4 + 0];
        float gt = 1.f / (1.f + __expf(-gp));
        r.x = fmaxf(gt * h.x + (1.f - gt) * d.x, 0.f);
    }
    {
        float gp = a.y + b.y + bin[c4 + 1] + bout[c4 + 1];
        float gt = 1.f / (1.f + __expf(-gp));
        r.y = fmaxf(gt * h.y + (1.f - gt) * d.y, 0.f);
    }
    {
        float gp = a.z + b.z + bin[c4 + 2] + bout[c4 + 2];
        float gt = 1.f / (1.f + __expf(-gp));
        r.z = fmaxf(gt * h.z + (1.f - gt) * d.z, 0.f);
    }
    {
        float gp = a.w + b.w + bin[c4 + 3] + bout[c4 + 3];
        float gt = 1.f / (1.f + __expf(-gp));
        r.w = fmaxf(gt * h.w + (1.f - gt) * d.w, 0.f);
    }
    ((float4*)hout)[i] = r;
}

__global__ __launch_bounds__(256) void pool_kernel(const float* __restrict__ h,
                                                   const int* __restrict__ batch,
                                                   float* __restrict__ pooled,
                                                   float* __restrict__ cnt) {
    int i = blockIdx.x * blockDim.x + threadIdx.x;
    if (i >= N_NODES * 128) return;
    int n = i >> 7, c = i & 127;
    int b = batch[n];
    atomicAdd(&pooled[b * 128 + c], h[i]);
    if (c == 0) atomicAdd(&cnt[b], 1.f);
}

__global__ __launch_bounds__(128) void head_kernel(const float* __restrict__ pooled,
                                                   const float* __restrict__ cnt,
                                                   const float* __restrict__ fc1W,
                                                   const float* __restrict__ fc1b,
                                                   const float* __restrict__ fc3W,
                                                   const float* __restrict__ fc3b,
                                                   float* __restrict__ out) {
    int gid = blockIdx.x, t = threadIdx.x;
    __shared__ float hg[128];
    __shared__ float a1[128];
    float cc = fmaxf(cnt[gid], 1.f);
    hg[t] = pooled[gid * 128 + t] / cc;
    __syncthreads();
    float s = fc1b[t];
    for (int c = 0; c < 128; c++) s = fmaf(hg[c], fc1W[c * 128 + t], s);
    a1[t] = fmaxf(s, 0.f);
    __syncthreads();
    if (t < 16) {
        float o = fc3b[t];
        for (int j = 0; j < 128; j++) o = fmaf(a1[j], fc3W[j * 16 + t], o);
        out[gid * 16 + t] = o;
    }
}

extern "C" void kernel_launch(void* const* d_in, const int* in_sizes, int n_in,
                              void* d_out, int out_size, void* d_ws, size_t ws_size,
                              hipStream_t stream) {
    const float* x       = (const float*)d_in[0];
    const int*   ei      = (const int*)d_in[1];
    const int*   batch   = (const int*)d_in[2];
    const float* W       = (const float*)d_in[3];
    const float* att_src = (const float*)d_in[4];
    const float* att_dst = (const float*)d_in[5];
    const float* conv_b  = (const float*)d_in[6];
    const float* gamma   = (const float*)d_in[7];
    const float* beta    = (const float*)d_in[8];
    const float* sk_Win  = (const float*)d_in[9];
    const float* sk_bin  = (const float*)d_in[10];
    const float* sk_Wout = (const float*)d_in[11];
    const float* sk_bout = (const float*)d_in[12];
    const float* fc1_W   = (const float*)d_in[13];
    const float* fc1_b   = (const float*)d_in[14];
    const float* fc3_W   = (const float*)d_in[15];
    const float* fc3_b   = (const float*)d_in[16];
    float* out = (float*)d_out;
    const int* ei0 = ei;
    const int* ei1 = ei + N_EDGES;

    float* ws = (float*)d_ws;
    size_t o = 0;
    float* hfull  = ws + o; o += (size_t)N_NODES * 512;
    float* gbuf   = ws + o; o += (size_t)N_NODES * 128;
    float* hbn    = ws + o; o += (size_t)N_NODES * 128;
    float* hA     = ws + o; o += (size_t)N_NODES * 128;
    float* hB     = ws + o; o += (size_t)N_NODES * 128;
    float* als    = ws + o; o += N_NODES * 4;
    float* ald    = ws + o; o += N_NODES * 4;
    float* bnsum  = ws + o; o += 128;
    float* bnsum2 = ws + o; o += 128;
    float* bnp    = ws + o; o += 256;
    float* pooled = ws + o; o += NGRAPH * 128;
    float* cnt    = ws + o; o += NGRAPH;
    int* deg      = (int*)(ws + o); o += N_NODES;
    int* rowptr   = (int*)(ws + o); o += N_NODES + 1;
    int* wofs     = (int*)(ws + o); o += N_NODES;
    int* csr_src  = (int*)(ws + o); o += ETOT;
    // t1/t2 alias hfull (hfull dead after gat_gather)
    float* t1 = hfull;
    float* t2 = hfull + (size_t)N_NODES * 128;

    // ---- CSR build (edge_index constant across layers) ----
    hipMemsetAsync(deg, 0, N_NODES * 4, stream);
    deg_kernel<<<(ETOT + 255) / 256, 256, 0, stream>>>(ei1, deg);
    scan_kernel<<<1, 1024, 0, stream>>>(deg, rowptr, wofs);
    scatter_kernel<<<(ETOT + 255) / 256, 256, 0, stream>>>(ei0, ei1, wofs, csr_src);

    const float* hin = x;
    float* hout = hA;
    for (int l = 0; l < 3; l++) {
        hipMemsetAsync(bnsum,  0, 128 * 4, stream);
        hipMemsetAsync(bnsum2, 0, 128 * 4, stream);

        gemm_k128<<<dim3(469, 8), 256, 0, stream>>>(hin, W + (size_t)l * 128 * 512, hfull, N_NODES, 512);
        alphas_kernel<<<7500, 256, 0, stream>>>(hfull, att_src + l * 512, att_dst + l * 512, als, ald);
        gat_gather<<<1024, 256, 0, stream>>>(rowptr, csr_src, als, ald, hfull,
                                             conv_b + l * 128, gbuf, bnsum, bnsum2);
        bn_final<<<1, 128, 0, stream>>>(bnsum, bnsum2, gamma + l * 128, beta + l * 128, bnp);
        hbn_kernel<<<(N_NODES * 32 + 255) / 256, 256, 0, stream>>>(gbuf, bnp, hbn);
        gemm_k128<<<dim3(469, 2), 256, 0, stream>>>(hin, sk_Win + (size_t)l * 128 * 128, t1, N_NODES, 128);
        gemm_k128<<<dim3(469, 2), 256, 0, stream>>>(hbn, sk_Wout + (size_t)l * 128 * 128, t2, N_NODES, 128);
        gate_kernel<<<(N_NODES * 32 + 255) / 256, 256, 0, stream>>>(t1, t2, hbn, hin,
                                                                    sk_bin + l * 128, sk_bout + l * 128, hout);
        hin = hout;
        hout = (hout == hA) ? hB : hA;
    }

    hipMemsetAsync(pooled, 0, NGRAPH * 128 * 4, stream);
    hipMemsetAsync(cnt,    0, NGRAPH * 4, stream);
    pool_kernel<<<(N_NODES * 128 + 255) / 256, 256, 0, stream>>>(hin, batch, pooled, cnt);
    head_kernel<<<NGRAPH, 128, 0, stream>>>(pooled, cnt, fc1_W, fc1_b, fc3_W, fc3_b, out);
}

// Round 3
// 721.205 us; speedup vs baseline: 2.9336x; 1.3570x over previous
//
#include <hip/hip_runtime.h>
#include <hip/hip_bf16.h>

#define N_NODES 30000
#define N_EDGES 240000
#define ETOT    (N_EDGES + N_NODES)   // 270000 (self loops appended)
#define NGRAPH  128

typedef __attribute__((ext_vector_type(8))) short bf16x8;
typedef __attribute__((ext_vector_type(4))) short bf16x4;
typedef __attribute__((ext_vector_type(4))) float f32x4;

__device__ __forceinline__ unsigned short f2bf(float f) {
    unsigned u = __float_as_uint(f);
    u += 0x7fff + ((u >> 16) & 1);        // round-to-nearest-even
    return (unsigned short)(u >> 16);
}
__device__ __forceinline__ float bf2f(unsigned short h) {
    return __uint_as_float(((unsigned)h) << 16);
}

// ---------- weight transpose + hi/lo bf16 split (once per call) ----------
// W: 3x[128k x 512n] -> wt[l][n][k]; Win/Wout: 3x[128k x 128n] -> [l][n][k]
__global__ __launch_bounds__(256) void conv_weights(const float* __restrict__ W,
                                                    const float* __restrict__ Win,
                                                    const float* __restrict__ Wout,
                                                    short* __restrict__ wt_hi, short* __restrict__ wt_lo,
                                                    short* __restrict__ wint_hi, short* __restrict__ wint_lo,
                                                    short* __restrict__ woutt_hi, short* __restrict__ woutt_lo) {
    int i = blockIdx.x * 256 + threadIdx.x;
    float v; short* dh; short* dl; int di;
    if (i < 196608) {                       // 3*512*128
        int l = i >> 16, r = i & 65535;
        int n = r >> 7, k = r & 127;
        v = W[(size_t)l * 65536 + k * 512 + n];
        dh = wt_hi; dl = wt_lo; di = i;
    } else if (i < 245760) {                // + 3*128*128
        int j = i - 196608;
        int l = j >> 14, r = j & 16383;
        int n = r >> 7, k = r & 127;
        v = Win[(size_t)l * 16384 + k * 128 + n];
        dh = wint_hi; dl = wint_lo; di = j;
    } else if (i < 294912) {
        int j = i - 245760;
        int l = j >> 14, r = j & 16383;
        int n = r >> 7, k = r & 127;
        v = Wout[(size_t)l * 16384 + k * 128 + n];
        dh = woutt_hi; dl = woutt_lo; di = j;
    } else return;
    unsigned short hi = f2bf(v);
    unsigned short lo = f2bf(v - bf2f(hi));
    dh[di] = (short)hi; dl[di] = (short)lo;
}

// ---------- MFMA GEMM: C[M,N] = A[M,128] @ B[128,N], Bt pre-transposed [N][128] ----
// split bf16: acc = Ah*Bh + Al*Bh + Ah*Bl  (~fp32 precision)
__global__ __launch_bounds__(256) void gemm_mfma(const float* __restrict__ A,
                                                 const short* __restrict__ Bth,
                                                 const short* __restrict__ Btl,
                                                 float* __restrict__ C, int N) {
    __shared__ short As_hi[64 * 136];
    __shared__ short As_lo[64 * 136];
    const int bm = blockIdx.x * 64;
    const int bn = blockIdx.y * 64;
    const int t  = threadIdx.x;
#pragma unroll
    for (int i = 0; i < 8; i++) {
        int idx4 = t + i * 256;
        int row = idx4 >> 5, c4 = (idx4 & 31) << 2;
        float4 v = make_float4(0.f, 0.f, 0.f, 0.f);
        if (bm + row < N_NODES) v = *(const float4*)(A + (size_t)(bm + row) * 128 + c4);
        unsigned short h0 = f2bf(v.x), h1 = f2bf(v.y), h2 = f2bf(v.z), h3 = f2bf(v.w);
        unsigned short l0 = f2bf(v.x - bf2f(h0)), l1 = f2bf(v.y - bf2f(h1));
        unsigned short l2 = f2bf(v.z - bf2f(h2)), l3 = f2bf(v.w - bf2f(h3));
        *(bf16x4*)(As_hi + row * 136 + c4) = (bf16x4){(short)h0, (short)h1, (short)h2, (short)h3};
        *(bf16x4*)(As_lo + row * 136 + c4) = (bf16x4){(short)l0, (short)l1, (short)l2, (short)l3};
    }
    __syncthreads();

    const int w = t >> 6, lane = t & 63;
    const int wr = w >> 1, wc = w & 1;
    const int lr = lane & 15, lg = lane >> 4;
    f32x4 acc[2][2] = {};
    const size_t bofs0 = (size_t)(bn + wc * 32 + lr) * 128 + lg * 8;
#pragma unroll
    for (int kk = 0; kk < 4; kk++) {
        bf16x8 ah[2], al[2], bh[2], bl[2];
#pragma unroll
        for (int ni = 0; ni < 2; ni++) {
            size_t o = bofs0 + (size_t)ni * 16 * 128 + kk * 32;
            bh[ni] = *(const bf16x8*)(Bth + o);
            bl[ni] = *(const bf16x8*)(Btl + o);
        }
        int ko = kk * 32 + lg * 8;
#pragma unroll
        for (int mi = 0; mi < 2; mi++) {
            int r = wr * 32 + mi * 16 + lr;
            ah[mi] = *(const bf16x8*)(As_hi + r * 136 + ko);
            al[mi] = *(const bf16x8*)(As_lo + r * 136 + ko);
        }
#pragma unroll
        for (int mi = 0; mi < 2; mi++)
#pragma unroll
            for (int ni = 0; ni < 2; ni++) {
                acc[mi][ni] = __builtin_amdgcn_mfma_f32_16x16x32_bf16(ah[mi], bh[ni], acc[mi][ni], 0, 0, 0);
                acc[mi][ni] = __builtin_amdgcn_mfma_f32_16x16x32_bf16(al[mi], bh[ni], acc[mi][ni], 0, 0, 0);
                acc[mi][ni] = __builtin_amdgcn_mfma_f32_16x16x32_bf16(ah[mi], bl[ni], acc[mi][ni], 0, 0, 0);
            }
    }
#pragma unroll
    for (int mi = 0; mi < 2; mi++) {
        int m0 = bm + wr * 32 + mi * 16 + lg * 4;
#pragma unroll
        for (int ni = 0; ni < 2; ni++) {
            int n = bn + wc * 32 + ni * 16 + lr;
#pragma unroll
            for (int r = 0; r < 4; r++) {
                int m = m0 + r;
                if (m < N_NODES) C[(size_t)m * N + n] = acc[mi][ni][r];
            }
        }
    }
}

// ---------- fused skip: P = hin@Win + bn(g)@Wout ; gate epilogue -> hout ----------
__global__ __launch_bounds__(256) void skip_gate(const float* __restrict__ hin,
                                                 const float* __restrict__ g,
                                                 const float* __restrict__ bnp,
                                                 const short* __restrict__ w1h, const short* __restrict__ w1l,
                                                 const short* __restrict__ w2h, const short* __restrict__ w2l,
                                                 const float* __restrict__ bin, const float* __restrict__ bout,
                                                 float* __restrict__ hout) {
    __shared__ short A1h[64 * 136], A1l[64 * 136], A2h[64 * 136], A2l[64 * 136];
    const int bm = blockIdx.x * 64;
    const int bn = blockIdx.y * 64;
    const int t  = threadIdx.x;
#pragma unroll
    for (int i = 0; i < 8; i++) {
        int idx4 = t + i * 256;
        int row = idx4 >> 5, c4 = (idx4 & 31) << 2;
        float4 v1 = make_float4(0.f, 0.f, 0.f, 0.f);
        float4 v2 = make_float4(0.f, 0.f, 0.f, 0.f);
        if (bm + row < N_NODES) {
            v1 = *(const float4*)(hin + (size_t)(bm + row) * 128 + c4);
            float4 gv = *(const float4*)(g + (size_t)(bm + row) * 128 + c4);
            float4 sc = *(const float4*)(bnp + c4);
            float4 sh = *(const float4*)(bnp + 128 + c4);
            v2.x = fmaf(sc.x, gv.x, sh.x); v2.y = fmaf(sc.y, gv.y, sh.y);
            v2.z = fmaf(sc.z, gv.z, sh.z); v2.w = fmaf(sc.w, gv.w, sh.w);
        }
        unsigned short a0 = f2bf(v1.x), a1 = f2bf(v1.y), a2 = f2bf(v1.z), a3 = f2bf(v1.w);
        *(bf16x4*)(A1h + row * 136 + c4) = (bf16x4){(short)a0, (short)a1, (short)a2, (short)a3};
        *(bf16x4*)(A1l + row * 136 + c4) = (bf16x4){(short)f2bf(v1.x - bf2f(a0)), (short)f2bf(v1.y - bf2f(a1)),
                                                    (short)f2bf(v1.z - bf2f(a2)), (short)f2bf(v1.w - bf2f(a3))};
        unsigned short b0 = f2bf(v2.x), b1 = f2bf(v2.y), b2 = f2bf(v2.z), b3 = f2bf(v2.w);
        *(bf16x4*)(A2h + row * 136 + c4) = (bf16x4){(short)b0, (short)b1, (short)b2, (short)b3};
        *(bf16x4*)(A2l + row * 136 + c4) = (bf16x4){(short)f2bf(v2.x - bf2f(b0)), (short)f2bf(v2.y - bf2f(b1)),
                                                    (short)f2bf(v2.z - bf2f(b2)), (short)f2bf(v2.w - bf2f(b3))};
    }
    __syncthreads();

    const int w = t >> 6, lane = t & 63;
    const int wr = w >> 1, wc = w & 1;
    const int lr = lane & 15, lg = lane >> 4;
    f32x4 acc[2][2] = {};
    const size_t bofs0 = (size_t)(bn + wc * 32 + lr) * 128 + lg * 8;
#pragma unroll
    for (int kk = 0; kk < 4; kk++) {
        bf16x8 a1f[2], a1g[2], a2f[2], a2g[2], b1h[2], b1l[2], b2h[2], b2l[2];
#pragma unroll
        for (int ni = 0; ni < 2; ni++) {
            size_t o = bofs0 + (size_t)ni * 16 * 128 + kk * 32;
            b1h[ni] = *(const bf16x8*)(w1h + o);
            b1l[ni] = *(const bf16x8*)(w1l + o);
            b2h[ni] = *(const bf16x8*)(w2h + o);
            b2l[ni] = *(const bf16x8*)(w2l + o);
        }
        int ko = kk * 32 + lg * 8;
#pragma unroll
        for (int mi = 0; mi < 2; mi++) {
            int r = wr * 32 + mi * 16 + lr;
            a1f[mi] = *(const bf16x8*)(A1h + r * 136 + ko);
            a1g[mi] = *(const bf16x8*)(A1l + r * 136 + ko);
            a2f[mi] = *(const bf16x8*)(A2h + r * 136 + ko);
            a2g[mi] = *(const bf16x8*)(A2l + r * 136 + ko);
        }
#pragma unroll
        for (int mi = 0; mi < 2; mi++)
#pragma unroll
            for (int ni = 0; ni < 2; ni++) {
                acc[mi][ni] = __builtin_amdgcn_mfma_f32_16x16x32_bf16(a1f[mi], b1h[ni], acc[mi][ni], 0, 0, 0);
                acc[mi][ni] = __builtin_amdgcn_mfma_f32_16x16x32_bf16(a1g[mi], b1h[ni], acc[mi][ni], 0, 0, 0);
                acc[mi][ni] = __builtin_amdgcn_mfma_f32_16x16x32_bf16(a1f[mi], b1l[ni], acc[mi][ni], 0, 0, 0);
                acc[mi][ni] = __builtin_amdgcn_mfma_f32_16x16x32_bf16(a2f[mi], b2h[ni], acc[mi][ni], 0, 0, 0);
                acc[mi][ni] = __builtin_amdgcn_mfma_f32_16x16x32_bf16(a2g[mi], b2h[ni], acc[mi][ni], 0, 0, 0);
                acc[mi][ni] = __builtin_amdgcn_mfma_f32_16x16x32_bf16(a2f[mi], b2l[ni], acc[mi][ni], 0, 0, 0);
            }
    }
#pragma unroll
    for (int mi = 0; mi < 2; mi++) {
        int m0 = bm + wr * 32 + mi * 16 + lg * 4;
#pragma unroll
        for (int ni = 0; ni < 2; ni++) {
            int n = bn + wc * 32 + ni * 16 + lr;
            float bsum = bin[n] + bout[n];
            float sc = bnp[n], sh = bnp[128 + n];
#pragma unroll
            for (int r = 0; r < 4; r++) {
                int m = m0 + r;
                if (m < N_NODES) {
                    float gv   = g[(size_t)m * 128 + n];
                    float hbnv = fmaf(sc, gv, sh);
                    float hv   = hin[(size_t)m * 128 + n];
                    float gt   = 1.f / (1.f + __expf(-(acc[mi][ni][r] + bsum)));
                    hout[(size_t)m * 128 + n] = fmaxf(gt * hbnv + (1.f - gt) * hv, 0.f);
                }
            }
        }
    }
}

// ---------------- attention logits per node ----------------
__global__ __launch_bounds__(256) void alphas_kernel(const float* __restrict__ hfull,
                                                     const float* __restrict__ att_s,
                                                     const float* __restrict__ att_d,
                                                     float* __restrict__ al_s,
                                                     float* __restrict__ al_d) {
    int n = blockIdx.x * 4 + (threadIdx.x >> 6);
    if (n >= N_NODES) return;
    int lane  = threadIdx.x & 63;
    int hd    = lane >> 4;
    int cbase = (lane & 15) * 8;
    const float* hr = hfull + (size_t)n * 512 + hd * 128 + cbase;
    const float* as = att_s + hd * 128 + cbase;
    const float* ad = att_d + hd * 128 + cbase;
    float ss = 0.f, sd = 0.f;
#pragma unroll
    for (int j = 0; j < 8; j++) { float v = hr[j]; ss = fmaf(v, as[j], ss); sd = fmaf(v, ad[j], sd); }
#pragma unroll
    for (int off = 1; off < 16; off <<= 1) { ss += __shfl_xor(ss, off); sd += __shfl_xor(sd, off); }
    if ((lane & 15) == 0) { al_s[n * 4 + hd] = ss; al_d[n * 4 + hd] = sd; }
}

// ---------------- CSR build ----------------
__global__ __launch_bounds__(256) void deg_kernel(const int* __restrict__ ei1,
                                                  int* __restrict__ deg) {
    int e = blockIdx.x * 256 + threadIdx.x;
    if (e >= ETOT) return;
    int d = (e < N_EDGES) ? ei1[e] : (e - N_EDGES);
    atomicAdd(&deg[d], 1);
}

__global__ __launch_bounds__(1024) void scan_kernel(const int* __restrict__ deg,
                                                    int* __restrict__ rowptr,
                                                    int* __restrict__ wofs) {
    const int CH = 30;
    int t = threadIdx.x;
    int base = t * CH;
    int s = 0;
    for (int j = 0; j < CH; j++) { int idx = base + j; if (idx < N_NODES) s += deg[idx]; }
    __shared__ int sums[1024];
    sums[t] = s;
    __syncthreads();
    for (int off = 1; off < 1024; off <<= 1) {
        int v = (t >= off) ? sums[t - off] : 0;
        __syncthreads();
        sums[t] += v;
        __syncthreads();
    }
    int run = sums[t] - s;
    for (int j = 0; j < CH; j++) {
        int idx = base + j;
        if (idx < N_NODES) { rowptr[idx] = run; wofs[idx] = run; run += deg[idx]; }
        else if (idx == N_NODES) { rowptr[N_NODES] = run; }
    }
}

__global__ __launch_bounds__(256) void scatter_kernel(const int* __restrict__ ei0,
                                                      const int* __restrict__ ei1,
                                                      int* __restrict__ wofs,
                                                      int* __restrict__ csr_src) {
    int e = blockIdx.x * 256 + threadIdx.x;
    if (e >= ETOT) return;
    int s = (e < N_EDGES) ? ei0[e] : (e - N_EDGES);
    int d = (e < N_EDGES) ? ei1[e] : (e - N_EDGES);
    int pos = atomicAdd(&wofs[d], 1);
    csr_src[pos] = s;
}

// ---------------- fused gather ----------------
__global__ __launch_bounds__(256) void gat_gather(const int* __restrict__ rowptr,
                                                  const int* __restrict__ csr_src,
                                                  const float* __restrict__ al_s,
                                                  const float* __restrict__ al_d,
                                                  const float* __restrict__ hfull,
                                                  const float* __restrict__ conv_b,
                                                  float* __restrict__ g,
                                                  float* __restrict__ bnsum,
                                                  float* __restrict__ bnsum2) {
    const int lane = threadIdx.x & 63;
    const int wib  = threadIdx.x >> 6;
    const int gwid = blockIdx.x * 4 + wib;
    const int nw   = gridDim.x * 4;
    const int h    = lane >> 4;
    const int sub  = lane & 15;
    float s1[8] = {}, s2[8] = {};

    for (int n = gwid; n < N_NODES; n += nw) {
        const int e0 = rowptr[n], e1 = rowptr[n + 1];
        const float ald_h = al_d[n * 4 + h];

        float mx = -1e30f;
        for (int i = e0 + sub; i < e1; i += 16) {
            int s = csr_src[i];
            float v = al_s[s * 4 + h] + ald_h;
            v = (v > 0.f) ? v : 0.2f * v;
            mx = fmaxf(mx, v);
        }
        mx = fmaxf(mx, __shfl_xor(mx, 1));
        mx = fmaxf(mx, __shfl_xor(mx, 2));
        mx = fmaxf(mx, __shfl_xor(mx, 4));
        mx = fmaxf(mx, __shfl_xor(mx, 8));

        float acc[8] = {};
        float zs = 0.f;
        int i = e0;
        for (; i + 1 < e1; i += 2) {
            int sA = csr_src[i], sB = csr_src[i + 1];
            float vA = al_s[sA * 4 + h] + ald_h; vA = (vA > 0.f) ? vA : 0.2f * vA;
            float vB = al_s[sB * 4 + h] + ald_h; vB = (vB > 0.f) ? vB : 0.2f * vB;
            const float4* pA = (const float4*)(hfull + (size_t)sA * 512) + (lane << 1);
            const float4* pB = (const float4*)(hfull + (size_t)sB * 512) + (lane << 1);
            float4 a0 = pA[0], a1 = pA[1];
            float4 b0 = pB[0], b1 = pB[1];
            float exA = __expf(vA - mx), exB = __expf(vB - mx);
            zs += exA + exB;
            acc[0] = fmaf(exA, a0.x, acc[0]); acc[1] = fmaf(exA, a0.y, acc[1]);
            acc[2] = fmaf(exA, a0.z, acc[2]); acc[3] = fmaf(exA, a0.w, acc[3]);
            acc[4] = fmaf(exA, a1.x, acc[4]); acc[5] = fmaf(exA, a1.y, acc[5]);
            acc[6] = fmaf(exA, a1.z, acc[6]); acc[7] = fmaf(exA, a1.w, acc[7]);
            acc[0] = fmaf(exB, b0.x, acc[0]); acc[1] = fmaf(exB, b0.y, acc[1]);
            acc[2] = fmaf(exB, b0.z, acc[2]); acc[3] = fmaf(exB, b0.w, acc[3]);
            acc[4] = fmaf(exB, b1.x, acc[4]); acc[5] = fmaf(exB, b1.y, acc[5]);
            acc[6] = fmaf(exB, b1.z, acc[6]); acc[7] = fmaf(exB, b1.w, acc[7]);
        }
        if (i < e1) {
            int sA = csr_src[i];
            float vA = al_s[sA * 4 + h] + ald_h; vA = (vA > 0.f) ? vA : 0.2f * vA;
            const float4* pA = (const float4*)(hfull + (size_t)sA * 512) + (lane << 1);
            float4 a0 = pA[0], a1 = pA[1];
            float exA = __expf(vA - mx);
            zs += exA;
            acc[0] = fmaf(exA, a0.x, acc[0]); acc[1] = fmaf(exA, a0.y, acc[1]);
            acc[2] = fmaf(exA, a0.z, acc[2]); acc[3] = fmaf(exA, a0.w, acc[3]);
            acc[4] = fmaf(exA, a1.x, acc[4]); acc[5] = fmaf(exA, a1.y, acc[5]);
            acc[6] = fmaf(exA, a1.z, acc[6]); acc[7] = fmaf(exA, a1.w, acc[7]);
        }

        float inv = 0.25f / (zs + 1e-16f);
#pragma unroll
        for (int j = 0; j < 8; j++) {
            float a = acc[j] * inv;
            a += __shfl_xor(a, 16);
            a += __shfl_xor(a, 32);
            acc[j] = a;
        }
        if (lane < 16) {
            float o[8];
#pragma unroll
            for (int j = 0; j < 8; j++) {
                float tv = acc[j] + conv_b[sub * 8 + j];
                o[j] = tv;
                s1[j] += tv;
                s2[j] = fmaf(tv, tv, s2[j]);
            }
            float* gp = g + (size_t)n * 128 + sub * 8;
            *(float4*)gp       = make_float4(o[0], o[1], o[2], o[3]);
            *(float4*)(gp + 4) = make_float4(o[4], o[5], o[6], o[7]);
        }
    }

    __shared__ float redA[4][128], redB[4][128];
    if (lane < 16) {
#pragma unroll
        for (int j = 0; j < 8; j++) {
            redA[wib][sub * 8 + j] = s1[j];
            redB[wib][sub * 8 + j] = s2[j];
        }
    }
    __syncthreads();
    int t = threadIdx.x;
    if (t < 128) {
        atomicAdd(&bnsum[t], redA[0][t] + redA[1][t] + redA[2][t] + redA[3][t]);
    } else {
        int c = t - 128;
        atomicAdd(&bnsum2[c], redB[0][c] + redB[1][c] + redB[2][c] + redB[3][c]);
    }
}

__global__ void bn_final(const float* __restrict__ s1, const float* __restrict__ s2,
                         const float* __restrict__ gamma, const float* __restrict__ beta,
                         float* __restrict__ bnp) {
    int c = threadIdx.x;
    float inv = 1.f / (float)N_NODES;
    float mu  = s1[c] * inv;
    float var = s2[c] * inv - mu * mu;
    float rs  = rsqrtf(var + 1e-5f);
    float sc  = gamma[c] * rs;
    bnp[c]       = sc;
    bnp[128 + c] = beta[c] - mu * sc;
}

// ---------------- pooling: sorted batch -> segment sums, no atomics ----------------
__global__ void bounds_kernel(const int* __restrict__ batch, int* __restrict__ gstart) {
    int t = threadIdx.x;
    if (t > NGRAPH) return;
    int lo = 0, hi = N_NODES;
    while (lo < hi) { int mid = (lo + hi) >> 1; if (batch[mid] < t) lo = mid + 1; else hi = mid; }
    gstart[t] = lo;
}

__global__ __launch_bounds__(256) void pool2_kernel(const float* __restrict__ h,
                                                    const int* __restrict__ gstart,
                                                    float* __restrict__ pooled) {
    int gid = blockIdx.x;
    int lo = gstart[gid], hi = gstart[gid + 1];
    int c = threadIdx.x & 127, half = threadIdx.x >> 7;
    float s = 0.f;
    for (int n = lo + half; n < hi; n += 2) s += h[(size_t)n * 128 + c];
    __shared__ float sh[256];
    sh[threadIdx.x] = s;
    __syncthreads();
    if (half == 0) {
        float cc = (float)(hi - lo);
        cc = fmaxf(cc, 1.f);
        pooled[gid * 128 + c] = (sh[c] + sh[c + 128]) / cc;
    }
}

__global__ __launch_bounds__(128) void head_kernel(const float* __restrict__ pooled,
                                                   const float* __restrict__ fc1W,
                                                   const float* __restrict__ fc1b,
                                                   const float* __restrict__ fc3W,
                                                   const float* __restrict__ fc3b,
                                                   float* __restrict__ out) {
    int gid = blockIdx.x, t = threadIdx.x;
    __shared__ float hg[128];
    __shared__ float a1[128];
    hg[t] = pooled[gid * 128 + t];
    __syncthreads();
    float s = fc1b[t];
    for (int c = 0; c < 128; c++) s = fmaf(hg[c], fc1W[c * 128 + t], s);
    a1[t] = fmaxf(s, 0.f);
    __syncthreads();
    if (t < 16) {
        float o = fc3b[t];
        for (int j = 0; j < 128; j++) o = fmaf(a1[j], fc3W[j * 16 + t], o);
        out[gid * 16 + t] = o;
    }
}

extern "C" void kernel_launch(void* const* d_in, const int* in_sizes, int n_in,
                              void* d_out, int out_size, void* d_ws, size_t ws_size,
                              hipStream_t stream) {
    const float* x       = (const float*)d_in[0];
    const int*   ei      = (const int*)d_in[1];
    const int*   batch   = (const int*)d_in[2];
    const float* W       = (const float*)d_in[3];
    const float* att_src = (const float*)d_in[4];
    const float* att_dst = (const float*)d_in[5];
    const float* conv_b  = (const float*)d_in[6];
    const float* gamma   = (const float*)d_in[7];
    const float* beta    = (const float*)d_in[8];
    const float* sk_Win  = (const float*)d_in[9];
    const float* sk_bin  = (const float*)d_in[10];
    const float* sk_Wout = (const float*)d_in[11];
    const float* sk_bout = (const float*)d_in[12];
    const float* fc1_W   = (const float*)d_in[13];
    const float* fc1_b   = (const float*)d_in[14];
    const float* fc3_W   = (const float*)d_in[15];
    const float* fc3_b   = (const float*)d_in[16];
    float* out = (float*)d_out;
    const int* ei0 = ei;
    const int* ei1 = ei + N_EDGES;

    float* ws = (float*)d_ws;
    size_t o = 0;
    float* hfull  = ws + o; o += (size_t)N_NODES * 512;
    float* gbuf   = ws + o; o += (size_t)N_NODES * 128;
    float* hA     = ws + o; o += (size_t)N_NODES * 128;
    float* hB     = ws + o; o += (size_t)N_NODES * 128;
    float* als    = ws + o; o += N_NODES * 4;
    float* ald    = ws + o; o += N_NODES * 4;
    float* bnsum  = ws + o; o += 256;      // [0:128)=sum, [128:256)=sumsq
    float* bnp    = ws + o; o += 256;
    float* pooled = ws + o; o += NGRAPH * 128;
    short* wt_hi   = (short*)(ws + o); o += 98304;   // 3*512*128 shorts
    short* wt_lo   = (short*)(ws + o); o += 98304;
    short* wint_hi = (short*)(ws + o); o += 24576;   // 3*128*128 shorts
    short* wint_lo = (short*)(ws + o); o += 24576;
    short* woutt_hi = (short*)(ws + o); o += 24576;
    short* woutt_lo = (short*)(ws + o); o += 24576;
    int* gstart   = (int*)(ws + o); o += 132;
    int* deg      = (int*)(ws + o); o += N_NODES;
    int* rowptr   = (int*)(ws + o); o += N_NODES + 4;
    int* wofs     = (int*)(ws + o); o += N_NODES;
    int* csr_src  = (int*)(ws + o); o += ETOT;

    conv_weights<<<1152, 256, 0, stream>>>(W, sk_Win, sk_Wout,
                                           wt_hi, wt_lo, wint_hi, wint_lo, woutt_hi, woutt_lo);

    hipMemsetAsync(deg, 0, N_NODES * 4, stream);
    deg_kernel<<<(ETOT + 255) / 256, 256, 0, stream>>>(ei1, deg);
    scan_kernel<<<1, 1024, 0, stream>>>(deg, rowptr, wofs);
    scatter_kernel<<<(ETOT + 255) / 256, 256, 0, stream>>>(ei0, ei1, wofs, csr_src);
    bounds_kernel<<<1, 256, 0, stream>>>(batch, gstart);

    const float* hin = x;
    float* hout = hA;
    for (int l = 0; l < 3; l++) {
        hipMemsetAsync(bnsum, 0, 256 * 4, stream);

        gemm_mfma<<<dim3(469, 8), 256, 0, stream>>>(hin, wt_hi + (size_t)l * 65536,
                                                    wt_lo + (size_t)l * 65536, hfull, 512);
        alphas_kernel<<<7500, 256, 0, stream>>>(hfull, att_src + l * 512, att_dst + l * 512, als, ald);
        gat_gather<<<1024, 256, 0, stream>>>(rowptr, csr_src, als, ald, hfull,
                                             conv_b + l * 128, gbuf, bnsum, bnsum + 128);
        bn_final<<<1, 128, 0, stream>>>(bnsum, bnsum + 128, gamma + l * 128, beta + l * 128, bnp);
        skip_gate<<<dim3(469, 2), 256, 0, stream>>>(hin, gbuf, bnp,
                                                    wint_hi + (size_t)l * 16384, wint_lo + (size_t)l * 16384,
                                                    woutt_hi + (size_t)l * 16384, woutt_lo + (size_t)l * 16384,
                                                    sk_bin + l * 128, sk_bout + l * 128, hout);
        hin = hout;
        hout = (hout == hA) ? hB : hA;
    }

    pool2_kernel<<<NGRAPH, 256, 0, stream>>>(hin, gstart, pooled);
    head_kernel<<<NGRAPH, 128, 0, stream>>>(pooled, fc1_W, fc1_b, fc3_W, fc3_b, out);
}

// Round 4
// 632.761 us; speedup vs baseline: 3.3437x; 1.1398x over previous
//
#include <hip/hip_runtime.h>
#include <hip/hip_bf16.h>

#define N_NODES 30000
#define N_EDGES 240000
#define ETOT    (N_EDGES + N_NODES)   // 270000 (self loops appended)
#define NGRAPH  128

typedef __attribute__((ext_vector_type(8))) short bf16x8;
typedef __attribute__((ext_vector_type(4))) short bf16x4;
typedef __attribute__((ext_vector_type(4))) float f32x4;

__device__ __forceinline__ unsigned short f2bf(float f) {
    unsigned u = __float_as_uint(f);
    u += 0x7fff + ((u >> 16) & 1);        // round-to-nearest-even
    return (unsigned short)(u >> 16);
}
__device__ __forceinline__ float bf2f(unsigned short h) {
    return __uint_as_float(((unsigned)h) << 16);
}

// ---------- weight transpose + hi/lo bf16 split (once per call) ----------
__global__ __launch_bounds__(256) void conv_weights(const float* __restrict__ W,
                                                    const float* __restrict__ Win,
                                                    const float* __restrict__ Wout,
                                                    short* __restrict__ wt_hi, short* __restrict__ wt_lo,
                                                    short* __restrict__ wint_hi, short* __restrict__ wint_lo,
                                                    short* __restrict__ woutt_hi, short* __restrict__ woutt_lo) {
    int i = blockIdx.x * 256 + threadIdx.x;
    float v; short* dh; short* dl; int di;
    if (i < 196608) {                       // 3*512*128
        int l = i >> 16, r = i & 65535;
        int n = r >> 7, k = r & 127;
        v = W[(size_t)l * 65536 + k * 512 + n];
        dh = wt_hi; dl = wt_lo; di = i;
    } else if (i < 245760) {                // + 3*128*128
        int j = i - 196608;
        int l = j >> 14, r = j & 16383;
        int n = r >> 7, k = r & 127;
        v = Win[(size_t)l * 16384 + k * 128 + n];
        dh = wint_hi; dl = wint_lo; di = j;
    } else if (i < 294912) {
        int j = i - 245760;
        int l = j >> 14, r = j & 16383;
        int n = r >> 7, k = r & 127;
        v = Wout[(size_t)l * 16384 + k * 128 + n];
        dh = woutt_hi; dl = woutt_lo; di = j;
    } else return;
    unsigned short hi = f2bf(v);
    unsigned short lo = f2bf(v - bf2f(hi));
    dh[di] = (short)hi; dl[di] = (short)lo;
}

// ---------- per-layer activation split: fp32 [N,128] -> bf16 hi/lo ----------
__global__ __launch_bounds__(256) void split_act(const float* __restrict__ A,
                                                 short* __restrict__ Ah,
                                                 short* __restrict__ Al) {
    int i = blockIdx.x * 256 + threadIdx.x;       // covers 8 floats each
    if (i >= N_NODES * 16) return;
    const float4* p = (const float4*)A + (size_t)i * 2;
    float4 v0 = p[0], v1 = p[1];
    float f[8] = {v0.x, v0.y, v0.z, v0.w, v1.x, v1.y, v1.z, v1.w};
    bf16x8 h, l;
#pragma unroll
    for (int j = 0; j < 8; j++) {
        unsigned short hh = f2bf(f[j]);
        h[j] = (short)hh;
        l[j] = (short)f2bf(f[j] - bf2f(hh));
    }
    *(bf16x8*)(Ah + (size_t)i * 8) = h;
    *(bf16x8*)(Al + (size_t)i * 8) = l;
}

// ---------- conv GEMM: hfullb[M,512](bf16) = A[M,128] @ W[128,512]; pre-split ----
// block: 64 rows x 128 cols; 4 waves: wr=w>>1 (row half), wc=w&1 (col half)
__global__ __launch_bounds__(256) void gemm_conv(const short* __restrict__ Ah,
                                                 const short* __restrict__ Al,
                                                 const short* __restrict__ Bth,
                                                 const short* __restrict__ Btl,
                                                 unsigned short* __restrict__ hfullb) {
    __shared__ short As_h[64 * 136];
    __shared__ short As_l[64 * 136];
    const int bm = blockIdx.x * 64;
    const int bn = blockIdx.y * 128;
    const int t  = threadIdx.x;
#pragma unroll
    for (int i = 0; i < 4; i++) {
        int idx8 = t + i * 256;              // 1024 ushort8 slots
        int row = idx8 >> 4, c8 = (idx8 & 15) << 3;
        bf16x8 vh = {}, vl = {};
        if (bm + row < N_NODES) {
            vh = *(const bf16x8*)(Ah + (size_t)(bm + row) * 128 + c8);
            vl = *(const bf16x8*)(Al + (size_t)(bm + row) * 128 + c8);
        }
        *(bf16x8*)(As_h + row * 136 + c8) = vh;
        *(bf16x8*)(As_l + row * 136 + c8) = vl;
    }
    __syncthreads();

    const int w = t >> 6, lane = t & 63;
    const int wr = w >> 1, wc = w & 1;
    const int lr = lane & 15, lg = lane >> 4;
    f32x4 acc[2][4] = {};
    const size_t bofs0 = (size_t)(bn + wc * 64 + lr) * 128 + lg * 8;
#pragma unroll
    for (int kk = 0; kk < 4; kk++) {
        bf16x8 ah[2], al[2], bh[4], bl[4];
#pragma unroll
        for (int ni = 0; ni < 4; ni++) {
            size_t o = bofs0 + (size_t)ni * 16 * 128 + kk * 32;
            bh[ni] = *(const bf16x8*)(Bth + o);
            bl[ni] = *(const bf16x8*)(Btl + o);
        }
        int ko = kk * 32 + lg * 8;
#pragma unroll
        for (int mi = 0; mi < 2; mi++) {
            int r = wr * 32 + mi * 16 + lr;
            ah[mi] = *(const bf16x8*)(As_h + r * 136 + ko);
            al[mi] = *(const bf16x8*)(As_l + r * 136 + ko);
        }
#pragma unroll
        for (int mi = 0; mi < 2; mi++)
#pragma unroll
            for (int ni = 0; ni < 4; ni++) {
                acc[mi][ni] = __builtin_amdgcn_mfma_f32_16x16x32_bf16(ah[mi], bh[ni], acc[mi][ni], 0, 0, 0);
                acc[mi][ni] = __builtin_amdgcn_mfma_f32_16x16x32_bf16(al[mi], bh[ni], acc[mi][ni], 0, 0, 0);
                acc[mi][ni] = __builtin_amdgcn_mfma_f32_16x16x32_bf16(ah[mi], bl[ni], acc[mi][ni], 0, 0, 0);
            }
    }
#pragma unroll
    for (int mi = 0; mi < 2; mi++) {
        int m0 = bm + wr * 32 + mi * 16 + lg * 4;
#pragma unroll
        for (int ni = 0; ni < 4; ni++) {
            int n = bn + wc * 64 + ni * 16 + lr;
#pragma unroll
            for (int r = 0; r < 4; r++) {
                int m = m0 + r;
                if (m < N_NODES) hfullb[(size_t)m * 512 + n] = f2bf(acc[mi][ni][r]);
            }
        }
    }
}

// ---------- fused skip: P = hin@Win + bn(g)@Wout ; gate epilogue -> hout ----------
__global__ __launch_bounds__(256) void skip_gate(const float* __restrict__ hin,
                                                 const short* __restrict__ hinh,
                                                 const short* __restrict__ hinl,
                                                 const float* __restrict__ g,
                                                 const float* __restrict__ bnp,
                                                 const short* __restrict__ w1h, const short* __restrict__ w1l,
                                                 const short* __restrict__ w2h, const short* __restrict__ w2l,
                                                 const float* __restrict__ bin, const float* __restrict__ bout,
                                                 float* __restrict__ hout) {
    __shared__ short A1h[64 * 136], A1l[64 * 136], A2h[64 * 136], A2l[64 * 136];
    const int bm = blockIdx.x * 64;
    const int bn = blockIdx.y * 64;
    const int t  = threadIdx.x;
    // A1: copy pre-split hin tiles
#pragma unroll
    for (int i = 0; i < 4; i++) {
        int idx8 = t + i * 256;
        int row = idx8 >> 4, c8 = (idx8 & 15) << 3;
        bf16x8 vh = {}, vl = {};
        if (bm + row < N_NODES) {
            vh = *(const bf16x8*)(hinh + (size_t)(bm + row) * 128 + c8);
            vl = *(const bf16x8*)(hinl + (size_t)(bm + row) * 128 + c8);
        }
        *(bf16x8*)(A1h + row * 136 + c8) = vh;
        *(bf16x8*)(A1l + row * 136 + c8) = vl;
    }
    // A2: bn(g) + split
#pragma unroll
    for (int i = 0; i < 8; i++) {
        int idx4 = t + i * 256;
        int row = idx4 >> 5, c4 = (idx4 & 31) << 2;
        float4 v2 = make_float4(0.f, 0.f, 0.f, 0.f);
        if (bm + row < N_NODES) {
            float4 gv = *(const float4*)(g + (size_t)(bm + row) * 128 + c4);
            float4 sc = *(const float4*)(bnp + c4);
            float4 sh = *(const float4*)(bnp + 128 + c4);
            v2.x = fmaf(sc.x, gv.x, sh.x); v2.y = fmaf(sc.y, gv.y, sh.y);
            v2.z = fmaf(sc.z, gv.z, sh.z); v2.w = fmaf(sc.w, gv.w, sh.w);
        }
        unsigned short b0 = f2bf(v2.x), b1 = f2bf(v2.y), b2 = f2bf(v2.z), b3 = f2bf(v2.w);
        *(bf16x4*)(A2h + row * 136 + c4) = (bf16x4){(short)b0, (short)b1, (short)b2, (short)b3};
        *(bf16x4*)(A2l + row * 136 + c4) = (bf16x4){(short)f2bf(v2.x - bf2f(b0)), (short)f2bf(v2.y - bf2f(b1)),
                                                    (short)f2bf(v2.z - bf2f(b2)), (short)f2bf(v2.w - bf2f(b3))};
    }
    __syncthreads();

    const int w = t >> 6, lane = t & 63;
    const int wr = w >> 1, wc = w & 1;
    const int lr = lane & 15, lg = lane >> 4;
    f32x4 acc[2][2] = {};
    const size_t bofs0 = (size_t)(bn + wc * 32 + lr) * 128 + lg * 8;
#pragma unroll
    for (int kk = 0; kk < 4; kk++) {
        bf16x8 a1f[2], a1g[2], a2f[2], a2g[2], b1h[2], b1l[2], b2h[2], b2l[2];
#pragma unroll
        for (int ni = 0; ni < 2; ni++) {
            size_t o = bofs0 + (size_t)ni * 16 * 128 + kk * 32;
            b1h[ni] = *(const bf16x8*)(w1h + o);
            b1l[ni] = *(const bf16x8*)(w1l + o);
            b2h[ni] = *(const bf16x8*)(w2h + o);
            b2l[ni] = *(const bf16x8*)(w2l + o);
        }
        int ko = kk * 32 + lg * 8;
#pragma unroll
        for (int mi = 0; mi < 2; mi++) {
            int r = wr * 32 + mi * 16 + lr;
            a1f[mi] = *(const bf16x8*)(A1h + r * 136 + ko);
            a1g[mi] = *(const bf16x8*)(A1l + r * 136 + ko);
            a2f[mi] = *(const bf16x8*)(A2h + r * 136 + ko);
            a2g[mi] = *(const bf16x8*)(A2l + r * 136 + ko);
        }
#pragma unroll
        for (int mi = 0; mi < 2; mi++)
#pragma unroll
            for (int ni = 0; ni < 2; ni++) {
                acc[mi][ni] = __builtin_amdgcn_mfma_f32_16x16x32_bf16(a1f[mi], b1h[ni], acc[mi][ni], 0, 0, 0);
                acc[mi][ni] = __builtin_amdgcn_mfma_f32_16x16x32_bf16(a1g[mi], b1h[ni], acc[mi][ni], 0, 0, 0);
                acc[mi][ni] = __builtin_amdgcn_mfma_f32_16x16x32_bf16(a1f[mi], b1l[ni], acc[mi][ni], 0, 0, 0);
                acc[mi][ni] = __builtin_amdgcn_mfma_f32_16x16x32_bf16(a2f[mi], b2h[ni], acc[mi][ni], 0, 0, 0);
                acc[mi][ni] = __builtin_amdgcn_mfma_f32_16x16x32_bf16(a2g[mi], b2h[ni], acc[mi][ni], 0, 0, 0);
                acc[mi][ni] = __builtin_amdgcn_mfma_f32_16x16x32_bf16(a2f[mi], b2l[ni], acc[mi][ni], 0, 0, 0);
            }
    }
#pragma unroll
    for (int mi = 0; mi < 2; mi++) {
        int m0 = bm + wr * 32 + mi * 16 + lg * 4;
#pragma unroll
        for (int ni = 0; ni < 2; ni++) {
            int n = bn + wc * 32 + ni * 16 + lr;
            float bsum = bin[n] + bout[n];
            float sc = bnp[n], sh = bnp[128 + n];
#pragma unroll
            for (int r = 0; r < 4; r++) {
                int m = m0 + r;
                if (m < N_NODES) {
                    float gv   = g[(size_t)m * 128 + n];
                    float hbnv = fmaf(sc, gv, sh);
                    float hv   = hin[(size_t)m * 128 + n];
                    float gt   = 1.f / (1.f + __expf(-(acc[mi][ni][r] + bsum)));
                    hout[(size_t)m * 128 + n] = fmaxf(gt * hbnv + (1.f - gt) * hv, 0.f);
                }
            }
        }
    }
}

// ---------------- attention logits per node (bf16 hfull) ----------------
__global__ __launch_bounds__(256) void alphas_kernel(const unsigned short* __restrict__ hfullb,
                                                     const float* __restrict__ att_s,
                                                     const float* __restrict__ att_d,
                                                     float* __restrict__ al_s,
                                                     float* __restrict__ al_d) {
    int n = blockIdx.x * 4 + (threadIdx.x >> 6);
    if (n >= N_NODES) return;
    int lane  = threadIdx.x & 63;
    int hd    = lane >> 4;
    int cbase = (lane & 15) * 8;
    const unsigned short* hr = hfullb + (size_t)n * 512 + hd * 128 + cbase;
    const float* as = att_s + hd * 128 + cbase;
    const float* ad = att_d + hd * 128 + cbase;
    bf16x8 hv = *(const bf16x8*)hr;
    float ss = 0.f, sd = 0.f;
#pragma unroll
    for (int j = 0; j < 8; j++) {
        float v = bf2f((unsigned short)hv[j]);
        ss = fmaf(v, as[j], ss); sd = fmaf(v, ad[j], sd);
    }
#pragma unroll
    for (int off = 1; off < 16; off <<= 1) { ss += __shfl_xor(ss, off); sd += __shfl_xor(sd, off); }
    if ((lane & 15) == 0) { al_s[n * 4 + hd] = ss; al_d[n * 4 + hd] = sd; }
}

// ---------------- CSR build ----------------
__global__ __launch_bounds__(256) void deg_kernel(const int* __restrict__ ei1,
                                                  int* __restrict__ deg) {
    int e = blockIdx.x * 256 + threadIdx.x;
    if (e >= ETOT) return;
    int d = (e < N_EDGES) ? ei1[e] : (e - N_EDGES);
    atomicAdd(&deg[d], 1);
}

__global__ __launch_bounds__(1024) void scan_kernel(const int* __restrict__ deg,
                                                    int* __restrict__ rowptr,
                                                    int* __restrict__ wofs) {
    const int CH = 30;
    int t = threadIdx.x;
    int base = t * CH;
    int s = 0;
    for (int j = 0; j < CH; j++) { int idx = base + j; if (idx < N_NODES) s += deg[idx]; }
    __shared__ int sums[1024];
    sums[t] = s;
    __syncthreads();
    for (int off = 1; off < 1024; off <<= 1) {
        int v = (t >= off) ? sums[t - off] : 0;
        __syncthreads();
        sums[t] += v;
        __syncthreads();
    }
    int run = sums[t] - s;
    for (int j = 0; j < CH; j++) {
        int idx = base + j;
        if (idx < N_NODES) { rowptr[idx] = run; wofs[idx] = run; run += deg[idx]; }
        else if (idx == N_NODES) { rowptr[N_NODES] = run; }
    }
}

__global__ __launch_bounds__(256) void scatter_kernel(const int* __restrict__ ei0,
                                                      const int* __restrict__ ei1,
                                                      int* __restrict__ wofs,
                                                      int* __restrict__ csr_src) {
    int e = blockIdx.x * 256 + threadIdx.x;
    if (e >= ETOT) return;
    int s = (e < N_EDGES) ? ei0[e] : (e - N_EDGES);
    int d = (e < N_EDGES) ? ei1[e] : (e - N_EDGES);
    int pos = atomicAdd(&wofs[d], 1);
    csr_src[pos] = s;
}

// ---------------- fused gather (bf16 messages) ----------------
__global__ __launch_bounds__(256) void gat_gather(const int* __restrict__ rowptr,
                                                  const int* __restrict__ csr_src,
                                                  const float* __restrict__ al_s,
                                                  const float* __restrict__ al_d,
                                                  const unsigned short* __restrict__ hfullb,
                                                  const float* __restrict__ conv_b,
                                                  float* __restrict__ g,
                                                  float* __restrict__ bnsum,
                                                  float* __restrict__ bnsum2) {
    const int lane = threadIdx.x & 63;
    const int wib  = threadIdx.x >> 6;
    const int gwid = blockIdx.x * 4 + wib;
    const int nw   = gridDim.x * 4;
    const int h    = lane >> 4;
    const int sub  = lane & 15;
    float s1[8] = {}, s2[8] = {};

    for (int n = gwid; n < N_NODES; n += nw) {
        const int e0 = rowptr[n], e1 = rowptr[n + 1];
        const float ald_h = al_d[n * 4 + h];

        float mx = -1e30f;
        for (int i = e0 + sub; i < e1; i += 16) {
            int s = csr_src[i];
            float v = al_s[s * 4 + h] + ald_h;
            v = (v > 0.f) ? v : 0.2f * v;
            mx = fmaxf(mx, v);
        }
        mx = fmaxf(mx, __shfl_xor(mx, 1));
        mx = fmaxf(mx, __shfl_xor(mx, 2));
        mx = fmaxf(mx, __shfl_xor(mx, 4));
        mx = fmaxf(mx, __shfl_xor(mx, 8));

        float acc[8] = {};
        float zs = 0.f;
        int i = e0;
        for (; i + 1 < e1; i += 2) {
            int sA = csr_src[i], sB = csr_src[i + 1];
            float vA = al_s[sA * 4 + h] + ald_h; vA = (vA > 0.f) ? vA : 0.2f * vA;
            float vB = al_s[sB * 4 + h] + ald_h; vB = (vB > 0.f) ? vB : 0.2f * vB;
            bf16x8 ha = *(const bf16x8*)(hfullb + (size_t)sA * 512 + lane * 8);
            bf16x8 hb = *(const bf16x8*)(hfullb + (size_t)sB * 512 + lane * 8);
            float exA = __expf(vA - mx), exB = __expf(vB - mx);
            zs += exA + exB;
#pragma unroll
            for (int j = 0; j < 8; j++) {
                acc[j] = fmaf(exA, bf2f((unsigned short)ha[j]), acc[j]);
                acc[j] = fmaf(exB, bf2f((unsigned short)hb[j]), acc[j]);
            }
        }
        if (i < e1) {
            int sA = csr_src[i];
            float vA = al_s[sA * 4 + h] + ald_h; vA = (vA > 0.f) ? vA : 0.2f * vA;
            bf16x8 ha = *(const bf16x8*)(hfullb + (size_t)sA * 512 + lane * 8);
            float exA = __expf(vA - mx);
            zs += exA;
#pragma unroll
            for (int j = 0; j < 8; j++)
                acc[j] = fmaf(exA, bf2f((unsigned short)ha[j]), acc[j]);
        }

        float inv = 0.25f / (zs + 1e-16f);
#pragma unroll
        for (int j = 0; j < 8; j++) {
            float a = acc[j] * inv;
            a += __shfl_xor(a, 16);
            a += __shfl_xor(a, 32);
            acc[j] = a;
        }
        if (lane < 16) {
            float o[8];
#pragma unroll
            for (int j = 0; j < 8; j++) {
                float tv = acc[j] + conv_b[sub * 8 + j];
                o[j] = tv;
                s1[j] += tv;
                s2[j] = fmaf(tv, tv, s2[j]);
            }
            float* gp = g + (size_t)n * 128 + sub * 8;
            *(float4*)gp       = make_float4(o[0], o[1], o[2], o[3]);
            *(float4*)(gp + 4) = make_float4(o[4], o[5], o[6], o[7]);
        }
    }

    __shared__ float redA[4][128], redB[4][128];
    if (lane < 16) {
#pragma unroll
        for (int j = 0; j < 8; j++) {
            redA[wib][sub * 8 + j] = s1[j];
            redB[wib][sub * 8 + j] = s2[j];
        }
    }
    __syncthreads();
    int t = threadIdx.x;
    if (t < 128) {
        atomicAdd(&bnsum[t], redA[0][t] + redA[1][t] + redA[2][t] + redA[3][t]);
    } else {
        int c = t - 128;
        atomicAdd(&bnsum2[c], redB[0][c] + redB[1][c] + redB[2][c] + redB[3][c]);
    }
}

__global__ void bn_final(const float* __restrict__ s1, const float* __restrict__ s2,
                         const float* __restrict__ gamma, const float* __restrict__ beta,
                         float* __restrict__ bnp) {
    int c = threadIdx.x;
    float inv = 1.f / (float)N_NODES;
    float mu  = s1[c] * inv;
    float var = s2[c] * inv - mu * mu;
    float rs  = rsqrtf(var + 1e-5f);
    float sc  = gamma[c] * rs;
    bnp[c]       = sc;
    bnp[128 + c] = beta[c] - mu * sc;
}

// ---------------- pooling: sorted batch -> segment sums, no atomics ----------------
__global__ void bounds_kernel(const int* __restrict__ batch, int* __restrict__ gstart) {
    int t = threadIdx.x;
    if (t > NGRAPH) return;
    int lo = 0, hi = N_NODES;
    while (lo < hi) { int mid = (lo + hi) >> 1; if (batch[mid] < t) lo = mid + 1; else hi = mid; }
    gstart[t] = lo;
}

__global__ __launch_bounds__(256) void pool2_kernel(const float* __restrict__ h,
                                                    const int* __restrict__ gstart,
                                                    float* __restrict__ pooled) {
    int gid = blockIdx.x;
    int lo = gstart[gid], hi = gstart[gid + 1];
    int c = threadIdx.x & 127, half = threadIdx.x >> 7;
    float s = 0.f;
    for (int n = lo + half; n < hi; n += 2) s += h[(size_t)n * 128 + c];
    __shared__ float sh[256];
    sh[threadIdx.x] = s;
    __syncthreads();
    if (half == 0) {
        float cc = (float)(hi - lo);
        cc = fmaxf(cc, 1.f);
        pooled[gid * 128 + c] = (sh[c] + sh[c + 128]) / cc;
    }
}

__global__ __launch_bounds__(128) void head_kernel(const float* __restrict__ pooled,
                                                   const float* __restrict__ fc1W,
                                                   const float* __restrict__ fc1b,
                                                   const float* __restrict__ fc3W,
                                                   const float* __restrict__ fc3b,
                                                   float* __restrict__ out) {
    int gid = blockIdx.x, t = threadIdx.x;
    __shared__ float hg[128];
    __shared__ float a1[128];
    hg[t] = pooled[gid * 128 + t];
    __syncthreads();
    float s = fc1b[t];
    for (int c = 0; c < 128; c++) s = fmaf(hg[c], fc1W[c * 128 + t], s);
    a1[t] = fmaxf(s, 0.f);
    __syncthreads();
    if (t < 16) {
        float o = fc3b[t];
        for (int j = 0; j < 128; j++) o = fmaf(a1[j], fc3W[j * 16 + t], o);
        out[gid * 16 + t] = o;
    }
}

extern "C" void kernel_launch(void* const* d_in, const int* in_sizes, int n_in,
                              void* d_out, int out_size, void* d_ws, size_t ws_size,
                              hipStream_t stream) {
    const float* x       = (const float*)d_in[0];
    const int*   ei      = (const int*)d_in[1];
    const int*   batch   = (const int*)d_in[2];
    const float* W       = (const float*)d_in[3];
    const float* att_src = (const float*)d_in[4];
    const float* att_dst = (const float*)d_in[5];
    const float* conv_b  = (const float*)d_in[6];
    const float* gamma   = (const float*)d_in[7];
    const float* beta    = (const float*)d_in[8];
    const float* sk_Win  = (const float*)d_in[9];
    const float* sk_bin  = (const float*)d_in[10];
    const float* sk_Wout = (const float*)d_in[11];
    const float* sk_bout = (const float*)d_in[12];
    const float* fc1_W   = (const float*)d_in[13];
    const float* fc1_b   = (const float*)d_in[14];
    const float* fc3_W   = (const float*)d_in[15];
    const float* fc3_b   = (const float*)d_in[16];
    float* out = (float*)d_out;
    const int* ei0 = ei;
    const int* ei1 = ei + N_EDGES;

    float* ws = (float*)d_ws;
    size_t o = 0;
    unsigned short* hfullb = (unsigned short*)(ws + o); o += (size_t)N_NODES * 256;  // bf16 [N,512]
    float* gbuf   = ws + o; o += (size_t)N_NODES * 128;
    float* hA     = ws + o; o += (size_t)N_NODES * 128;
    float* hB     = ws + o; o += (size_t)N_NODES * 128;
    short* hinh   = (short*)(ws + o); o += (size_t)N_NODES * 64;   // bf16 [N,128]
    short* hinl   = (short*)(ws + o); o += (size_t)N_NODES * 64;
    float* als    = ws + o; o += N_NODES * 4;
    float* ald    = ws + o; o += N_NODES * 4;
    float* bnsum  = ws + o; o += 256;      // [0:128)=sum, [128:256)=sumsq
    float* bnp    = ws + o; o += 256;
    float* pooled = ws + o; o += NGRAPH * 128;
    short* wt_hi   = (short*)(ws + o); o += 98304;   // 3*512*128 shorts
    short* wt_lo   = (short*)(ws + o); o += 98304;
    short* wint_hi = (short*)(ws + o); o += 24576;   // 3*128*128 shorts
    short* wint_lo = (short*)(ws + o); o += 24576;
    short* woutt_hi = (short*)(ws + o); o += 24576;
    short* woutt_lo = (short*)(ws + o); o += 24576;
    int* gstart   = (int*)(ws + o); o += 132;
    int* deg      = (int*)(ws + o); o += N_NODES;
    int* rowptr   = (int*)(ws + o); o += N_NODES + 4;
    int* wofs     = (int*)(ws + o); o += N_NODES;
    int* csr_src  = (int*)(ws + o); o += ETOT;

    conv_weights<<<1152, 256, 0, stream>>>(W, sk_Win, sk_Wout,
                                           wt_hi, wt_lo, wint_hi, wint_lo, woutt_hi, woutt_lo);

    hipMemsetAsync(deg, 0, N_NODES * 4, stream);
    deg_kernel<<<(ETOT + 255) / 256, 256, 0, stream>>>(ei1, deg);
    scan_kernel<<<1, 1024, 0, stream>>>(deg, rowptr, wofs);
    scatter_kernel<<<(ETOT + 255) / 256, 256, 0, stream>>>(ei0, ei1, wofs, csr_src);
    bounds_kernel<<<1, 256, 0, stream>>>(batch, gstart);

    const float* hin = x;
    float* hout = hA;
    for (int l = 0; l < 3; l++) {
        hipMemsetAsync(bnsum, 0, 256 * 4, stream);

        split_act<<<1875, 256, 0, stream>>>(hin, hinh, hinl);
        gemm_conv<<<dim3(469, 4), 256, 0, stream>>>(hinh, hinl,
                                                    wt_hi + (size_t)l * 65536, wt_lo + (size_t)l * 65536,
                                                    hfullb);
        alphas_kernel<<<7500, 256, 0, stream>>>(hfullb, att_src + l * 512, att_dst + l * 512, als, ald);
        gat_gather<<<1024, 256, 0, stream>>>(rowptr, csr_src, als, ald, hfullb,
                                             conv_b + l * 128, gbuf, bnsum, bnsum + 128);
        bn_final<<<1, 128, 0, stream>>>(bnsum, bnsum + 128, gamma + l * 128, beta + l * 128, bnp);
        skip_gate<<<dim3(469, 2), 256, 0, stream>>>(hin, hinh, hinl, gbuf, bnp,
                                                    wint_hi + (size_t)l * 16384, wint_lo + (size_t)l * 16384,
                                                    woutt_hi + (size_t)l * 16384, woutt_lo + (size_t)l * 16384,
                                                    sk_bin + l * 128, sk_bout + l * 128, hout);
        hin = hout;
        hout = (hout == hA) ? hB : hA;
    }

    pool2_kernel<<<NGRAPH, 256, 0, stream>>>(hin, gstart, pooled);
    head_kernel<<<NGRAPH, 128, 0, stream>>>(pooled, fc1_W, fc1_b, fc3_W, fc3_b, out);
}